// Round 1
// baseline (4431.704 us; speedup 1.0000x reference)
//
#include <hip/hip_runtime.h>

#define F_DIM 128

// ---- degree: deg[dst[e]] += 1 ------------------------------------------------
__global__ __launch_bounds__(256) void deg_kernel(const int* __restrict__ dst,
                                                  float* __restrict__ deg, int E) {
    int e = blockIdx.x * 256 + threadIdx.x;
    if (e < E) unsafeAtomicAdd(&deg[dst[e]], 1.0f);
}

// ---- dinv[i] = 1/sqrt(deg[i] + 1) (in place) --------------------------------
__global__ __launch_bounds__(256) void dinv_kernel(float* deg, int n) {
    int i = blockIdx.x * 256 + threadIdx.x;
    if (i < n) deg[i] = 1.0f / sqrtf(deg[i] + 1.0f);
}

// ---- Xp = X @ W + b ; W (128x128 f32 = 64KB) staged in LDS -------------------
// block = 256 threads; thread t computes row (blk*8 + t>>5), cols (t&31)*4 .. +3
__global__ __launch_bounds__(256) void gemm_kernel(const float* __restrict__ X,
                                                   const float* __restrict__ W,
                                                   const float* __restrict__ b,
                                                   float* __restrict__ Xp, int n_rows) {
    __shared__ float Wl[128 * 128];
    __shared__ float bl[128];
    {
        const float4* W4 = (const float4*)W;
        float4* Wl4 = (float4*)Wl;
        for (int i = threadIdx.x; i < 128 * 32; i += 256) Wl4[i] = W4[i];
        if (threadIdx.x < 128) bl[threadIdx.x] = b[threadIdx.x];
    }
    __syncthreads();
    const int c4 = (threadIdx.x & 31) * 4;
    const int rslot = threadIdx.x >> 5;
    int row = blockIdx.x * 8 + rslot;
    if (row >= n_rows) return;
    const float4* xrow = (const float4*)(X + (size_t)row * F_DIM);
    float4 acc = make_float4(bl[c4], bl[c4 + 1], bl[c4 + 2], bl[c4 + 3]);
#pragma unroll 8
    for (int k4 = 0; k4 < 32; ++k4) {
        float4 x = xrow[k4];
        const float* wbase = &Wl[(k4 * 4) * 128 + c4];
        float4 w0 = *(const float4*)(wbase);
        float4 w1 = *(const float4*)(wbase + 128);
        float4 w2 = *(const float4*)(wbase + 256);
        float4 w3 = *(const float4*)(wbase + 384);
        acc.x += x.x * w0.x + x.y * w1.x + x.z * w2.x + x.w * w3.x;
        acc.y += x.x * w0.y + x.y * w1.y + x.z * w2.y + x.w * w3.y;
        acc.z += x.x * w0.z + x.y * w1.z + x.z * w2.z + x.w * w3.z;
        acc.w += x.x * w0.w + x.y * w1.w + x.z * w2.w + x.w * w3.w;
    }
    *(float4*)&Xp[(size_t)row * F_DIM + c4] = acc;
}

// ---- out = dinv^2 * Xp (self-loop term; also initializes out) ----------------
__global__ __launch_bounds__(256) void init_kernel(const float* __restrict__ Xp,
                                                   const float* __restrict__ dinv,
                                                   float* __restrict__ out, int total4) {
    int i = blockIdx.x * 256 + threadIdx.x;
    if (i >= total4) return;
    int row = i >> 5;  // 32 float4 per row of 128
    float di = dinv[row];
    float s = di * di;
    float4 v = ((const float4*)Xp)[i];
    ((float4*)out)[i] = make_float4(v.x * s, v.y * s, v.z * s, v.w * s);
}

// ---- edge scatter: out[dst] += dinv[src]*dinv[dst] * Xp[src] -----------------
// 32 threads per edge, each handles a float4 of the 128 features.
__global__ __launch_bounds__(256) void scatter_kernel(const int* __restrict__ src,
                                                      const int* __restrict__ dst,
                                                      const float* __restrict__ dinv,
                                                      const float* __restrict__ Xp,
                                                      float* __restrict__ out, int E) {
    int gid = blockIdx.x * 256 + threadIdx.x;
    int e = gid >> 5;
    if (e >= E) return;
    int f4 = gid & 31;
    int s = src[e];
    int d = dst[e];
    float w = dinv[s] * dinv[d];
    float4 v = ((const float4*)(Xp + (size_t)s * F_DIM))[f4];
    float* o = out + (size_t)d * F_DIM + f4 * 4;
    unsafeAtomicAdd(o + 0, v.x * w);
    unsafeAtomicAdd(o + 1, v.y * w);
    unsafeAtomicAdd(o + 2, v.z * w);
    unsafeAtomicAdd(o + 3, v.w * w);
}

extern "C" void kernel_launch(void* const* d_in, const int* in_sizes, int n_in,
                              void* d_out, int out_size, void* d_ws, size_t ws_size,
                              hipStream_t stream) {
    const float* X[3] = {(const float*)d_in[0], (const float*)d_in[1], (const float*)d_in[2]};
    const int* ei[3] = {(const int*)d_in[3], (const int*)d_in[4], (const int*)d_in[5]};
    const float* W[3] = {(const float*)d_in[6], (const float*)d_in[8], (const float*)d_in[10]};
    const float* b[3] = {(const float*)d_in[7], (const float*)d_in[9], (const float*)d_in[11]};

    const int N = in_sizes[0] / F_DIM;      // 50000
    const int E = in_sizes[3] / 2;          // 800000
    float* out = (float*)d_out;

    // workspace layout: Xp [N*F], deg/dinv [N]
    float* Xp = (float*)d_ws;
    float* deg = Xp + (size_t)N * F_DIM;

    const int total4 = N * (F_DIM / 4);     // float4 count per array

    for (int g = 0; g < 3; ++g) {
        const int* srcp = ei[g];
        const int* dstp = ei[g] + E;
        float* outg = out + (size_t)g * N * F_DIM;

        hipMemsetAsync(deg, 0, (size_t)N * sizeof(float), stream);
        deg_kernel<<<(E + 255) / 256, 256, 0, stream>>>(dstp, deg, E);
        dinv_kernel<<<(N + 255) / 256, 256, 0, stream>>>(deg, N);
        gemm_kernel<<<(N + 7) / 8, 256, 0, stream>>>(X[g], W[g], b[g], Xp, N);
        init_kernel<<<(total4 + 255) / 256, 256, 0, stream>>>(Xp, deg, outg, total4);
        int sthreads = E * 32;
        scatter_kernel<<<(sthreads + 255) / 256, 256, 0, stream>>>(srcp, dstp, deg, Xp, outg, E);
    }
}

// Round 2
// 864.398 us; speedup vs baseline: 5.1269x; 5.1269x over previous
//
#include <hip/hip_runtime.h>

#define F_DIM 128

// ---- histogram: counts[dst[e]] += 1 (int) ------------------------------------
__global__ __launch_bounds__(256) void hist_kernel(const int* __restrict__ dst,
                                                   int* __restrict__ counts, int E) {
    int e = blockIdx.x * 256 + threadIdx.x;
    if (e < E) atomicAdd(&counts[dst[e]], 1);
}

// ---- single-block scan: counts -> exclusive offsets (+cursor copy, +dinv) ----
__global__ __launch_bounds__(1024) void scan_kernel(const int* __restrict__ counts,
                                                    int* __restrict__ offsets,
                                                    int* __restrict__ cursor,
                                                    float* __restrict__ dinv, int n) {
    __shared__ int buf[1024];
    __shared__ int carry_s;
    const int t = threadIdx.x;
    if (t == 0) carry_s = 0;
    __syncthreads();
    for (int base = 0; base < n; base += 4096) {
        int i0 = base + t * 4;
        int v0 = (i0 + 0 < n) ? counts[i0 + 0] : 0;
        int v1 = (i0 + 1 < n) ? counts[i0 + 1] : 0;
        int v2 = (i0 + 2 < n) ? counts[i0 + 2] : 0;
        int v3 = (i0 + 3 < n) ? counts[i0 + 3] : 0;
        int s = v0 + v1 + v2 + v3;
        buf[t] = s;
        __syncthreads();
        for (int off = 1; off < 1024; off <<= 1) {
            int x = (t >= off) ? buf[t - off] : 0;
            __syncthreads();
            buf[t] += x;
            __syncthreads();
        }
        int excl = carry_s + buf[t] - s;
        int o0 = excl, o1 = o0 + v0, o2 = o1 + v1, o3 = o2 + v2;
        if (i0 + 0 < n) { offsets[i0+0]=o0; cursor[i0+0]=o0; dinv[i0+0]=rsqrtf((float)v0+1.0f); }
        if (i0 + 1 < n) { offsets[i0+1]=o1; cursor[i0+1]=o1; dinv[i0+1]=rsqrtf((float)v1+1.0f); }
        if (i0 + 2 < n) { offsets[i0+2]=o2; cursor[i0+2]=o2; dinv[i0+2]=rsqrtf((float)v2+1.0f); }
        if (i0 + 3 < n) { offsets[i0+3]=o3; cursor[i0+3]=o3; dinv[i0+3]=rsqrtf((float)v3+1.0f); }
        __syncthreads();
        if (t == 1023) carry_s += buf[1023];
        __syncthreads();
    }
}

// ---- bucket-scatter: sorted_src[ticket(dst[e])] = src[e] ---------------------
__global__ __launch_bounds__(256) void build_kernel(const int* __restrict__ src,
                                                    const int* __restrict__ dst,
                                                    int* __restrict__ cursor,
                                                    int* __restrict__ sorted_src, int E) {
    int e = blockIdx.x * 256 + threadIdx.x;
    if (e >= E) return;
    int d = dst[e];
    int p = atomicAdd(&cursor[d], 1);
    sorted_src[p] = src[e];
}

// ---- Xps = dinv[row] * (X @ W + b); W + X tile staged in LDS -----------------
// block = 256 threads, 64 rows/block; thread t: rows (t>>5)*8..+7, cols (t&31)*4..+3
__global__ __launch_bounds__(256) void gemm_kernel(const float* __restrict__ X,
                                                   const float* __restrict__ W,
                                                   const float* __restrict__ b,
                                                   const float* __restrict__ dinv,
                                                   float* __restrict__ Xps, int n) {
    __shared__ float Wl[128 * 128];
    __shared__ float Xl[64 * 128];
    __shared__ float bl[128];
    const int t = threadIdx.x;
    const int row0blk = blockIdx.x * 64;
    {
        const float4* W4 = (const float4*)W;
        float4* Wl4 = (float4*)Wl;
        for (int i = t; i < 128 * 32; i += 256) Wl4[i] = W4[i];
        float4* Xl4 = (float4*)Xl;
        for (int i = t; i < 64 * 32; i += 256) {
            int r = row0blk + (i >> 5);
            Xl4[i] = (r < n) ? ((const float4*)X)[(size_t)r * 32 + (i & 31)]
                             : make_float4(0.f, 0.f, 0.f, 0.f);
        }
        if (t < 128) bl[t] = b[t];
    }
    __syncthreads();
    const int c4 = (t & 31) * 4;
    const int rg = t >> 5;
    float4 bias = *(const float4*)&bl[c4];
    float4 acc[8];
#pragma unroll
    for (int r = 0; r < 8; ++r) acc[r] = bias;
    for (int k4 = 0; k4 < 32; ++k4) {
        const float* wbase = &Wl[(k4 * 4) * 128 + c4];
        float4 w0 = *(const float4*)(wbase);
        float4 w1 = *(const float4*)(wbase + 128);
        float4 w2 = *(const float4*)(wbase + 256);
        float4 w3 = *(const float4*)(wbase + 384);
#pragma unroll
        for (int r = 0; r < 8; ++r) {
            float4 x = *(const float4*)&Xl[(rg * 8 + r) * 128 + k4 * 4];
            acc[r].x += x.x*w0.x + x.y*w1.x + x.z*w2.x + x.w*w3.x;
            acc[r].y += x.x*w0.y + x.y*w1.y + x.z*w2.y + x.w*w3.y;
            acc[r].z += x.x*w0.z + x.y*w1.z + x.z*w2.z + x.w*w3.z;
            acc[r].w += x.x*w0.w + x.y*w1.w + x.z*w2.w + x.w*w3.w;
        }
    }
#pragma unroll
    for (int r = 0; r < 8; ++r) {
        int row = row0blk + rg * 8 + r;
        if (row < n) {
            float dd = dinv[row];
            float4 v = acc[r];
            ((float4*)Xps)[(size_t)row * 32 + (c4 >> 2)] =
                make_float4(v.x * dd, v.y * dd, v.z * dd, v.w * dd);
        }
    }
}

// ---- aggregation: out[d] = dinv[d] * (Xps[d] + sum_{e in in(d)} Xps[src_e]) --
// one 64-lane wave per node; lane owns float2 (2 features)
__global__ __launch_bounds__(256) void agg_kernel(const int* __restrict__ sorted_src,
                                                  const int* __restrict__ offsets,
                                                  const int* __restrict__ counts,
                                                  const float* __restrict__ dinv,
                                                  const float* __restrict__ Xps,
                                                  float* __restrict__ out, int n) {
    int wave = (blockIdx.x * 256 + threadIdx.x) >> 6;
    if (wave >= n) return;
    int lane = threadIdx.x & 63;
    const float2* Xp2 = (const float2*)Xps;
    int beg = offsets[wave];
    int cnt = counts[wave];
    float2 acc = Xp2[(size_t)wave * 64 + lane];
    int j = 0;
    while (j < cnt) {
        int m = min(cnt - j, 64);
        int s = (j + lane < cnt) ? sorted_src[beg + j + lane] : 0;
        for (int k = 0; k < m; ++k) {
            int sk = __shfl(s, k, 64);
            float2 v = Xp2[(size_t)sk * 64 + lane];
            acc.x += v.x;
            acc.y += v.y;
        }
        j += m;
    }
    float dd = dinv[wave];
    ((float2*)out)[(size_t)wave * 64 + lane] = make_float2(acc.x * dd, acc.y * dd);
}

extern "C" void kernel_launch(void* const* d_in, const int* in_sizes, int n_in,
                              void* d_out, int out_size, void* d_ws, size_t ws_size,
                              hipStream_t stream) {
    const float* X[3] = {(const float*)d_in[0], (const float*)d_in[1], (const float*)d_in[2]};
    const int* ei[3] = {(const int*)d_in[3], (const int*)d_in[4], (const int*)d_in[5]};
    const float* W[3] = {(const float*)d_in[6], (const float*)d_in[8], (const float*)d_in[10]};
    const float* b[3] = {(const float*)d_in[7], (const float*)d_in[9], (const float*)d_in[11]};

    const int N = in_sizes[0] / F_DIM;  // 50000
    const int E = in_sizes[3] / 2;      // 800000
    float* out = (float*)d_out;

    // workspace layout
    float* Xps = (float*)d_ws;                         // N*128 f32 = 25.6 MB
    int* counts = (int*)(Xps + (size_t)N * F_DIM);     // N
    int* offsets = counts + N;                         // N
    int* cursor = offsets + N;                         // N
    float* dinv = (float*)(cursor + N);                // N
    int* sorted_src = (int*)(dinv + N);                // E = 3.2 MB

    for (int g = 0; g < 3; ++g) {
        const int* srcp = ei[g];
        const int* dstp = ei[g] + E;
        float* outg = out + (size_t)g * N * F_DIM;

        hipMemsetAsync(counts, 0, (size_t)N * sizeof(int), stream);
        hist_kernel<<<(E + 255) / 256, 256, 0, stream>>>(dstp, counts, E);
        scan_kernel<<<1, 1024, 0, stream>>>(counts, offsets, cursor, dinv, N);
        build_kernel<<<(E + 255) / 256, 256, 0, stream>>>(srcp, dstp, cursor, sorted_src, E);
        gemm_kernel<<<(N + 63) / 64, 256, 0, stream>>>(X[g], W[g], b[g], dinv, Xps, N);
        agg_kernel<<<(N * 64 + 255) / 256, 256, 0, stream>>>(sorted_src, offsets, counts,
                                                             dinv, Xps, outg, N);
    }
}

// Round 3
// 666.519 us; speedup vs baseline: 6.6490x; 1.2969x over previous
//
#include <hip/hip_runtime.h>

#define F_DIM 128
#define NG 3

struct GArgs {
    const int* src[NG]; const int* dst[NG];
    const float* X[NG]; const float* W[NG]; const float* b[NG];
    float* out[NG];
    float* Xps[NG]; int* counts[NG]; int* offsets[NG]; int* cursor[NG];
    float* dinv[NG]; int* sorted[NG];
    int* totals;  // [NG] global bucket cursors
};

// ---- histogram: counts[dst[e]] += 1 ------------------------------------------
__global__ __launch_bounds__(256) void hist_kernel(GArgs a, int g0, int E) {
    int g = g0 + blockIdx.y;
    int e = blockIdx.x * 256 + threadIdx.x;
    if (e < E) atomicAdd(&a.counts[g][a.dst[g][e]], 1);
}

// ---- offsets via wave-scan + one atomic per wave (order-free buckets) --------
__global__ __launch_bounds__(256) void offs_kernel(GArgs a, int g0, int n) {
    int g = g0 + blockIdx.y;
    int i = blockIdx.x * 256 + threadIdx.x;
    int lane = threadIdx.x & 63;
    int c = (i < n) ? a.counts[g][i] : 0;
    int v = c;
#pragma unroll
    for (int off = 1; off < 64; off <<= 1) {
        int u = __shfl_up(v, off, 64);
        if (lane >= off) v += u;
    }
    int wsum = __shfl(v, 63, 64);
    int base = 0;
    if (lane == 63) base = atomicAdd(&a.totals[g], wsum);
    base = __shfl(base, 63, 64);
    int off0 = base + v - c;  // exclusive within wave + wave base
    if (i < n) {
        a.offsets[g][i] = off0;
        a.cursor[g][i] = off0;
        a.dinv[g][i] = rsqrtf((float)c + 1.0f);
    }
}

// ---- bucket-scatter: sorted[ticket(dst[e])] = src[e] -------------------------
__global__ __launch_bounds__(256) void build_kernel(GArgs a, int g0, int E) {
    int g = g0 + blockIdx.y;
    int e = blockIdx.x * 256 + threadIdx.x;
    if (e >= E) return;
    int d = a.dst[g][e];
    int p = atomicAdd(&a.cursor[g][d], 1);
    a.sorted[g][p] = a.src[g][e];
}

// ---- Xps = dinv[row] * (X @ W + b); K-tiled W (16KB) + X tile (32KB) in LDS --
// 256 threads, 64 rows/block; thread t: rows (t>>5)*8..+7, cols (t&31)*4..+3
__global__ __launch_bounds__(256) void gemm_kernel(GArgs a, int g0, int n) {
    int g = g0 + blockIdx.y;
    __shared__ float Wl[32 * 128];
    __shared__ float Xl[64 * 128];
    __shared__ float bl[128];
    const int t = threadIdx.x;
    const int row0 = blockIdx.x * 64;
    const float* X = a.X[g];
    const float* W = a.W[g];
    {
        float4* Xl4 = (float4*)Xl;
        for (int i = t; i < 64 * 32; i += 256) {
            int r = row0 + (i >> 5);
            Xl4[i] = (r < n) ? ((const float4*)X)[(size_t)r * 32 + (i & 31)]
                             : make_float4(0.f, 0.f, 0.f, 0.f);
        }
        if (t < 128) bl[t] = a.b[g][t];
    }
    __syncthreads();
    const int c4 = (t & 31) * 4;
    const int rg = t >> 5;
    float4 bias = *(const float4*)&bl[c4];
    float4 acc[8];
#pragma unroll
    for (int r = 0; r < 8; ++r) acc[r] = bias;
    for (int kt = 0; kt < 4; ++kt) {
        {
            const float4* W4 = (const float4*)(W + kt * 32 * 128);
            float4* Wl4 = (float4*)Wl;
#pragma unroll
            for (int i = 0; i < 4; ++i) Wl4[t + i * 256] = W4[t + i * 256];
        }
        __syncthreads();
#pragma unroll
        for (int k4 = 0; k4 < 8; ++k4) {
            const float* wb = &Wl[(k4 * 4) * 128 + c4];
            float4 w0 = *(const float4*)(wb);
            float4 w1 = *(const float4*)(wb + 128);
            float4 w2 = *(const float4*)(wb + 256);
            float4 w3 = *(const float4*)(wb + 384);
#pragma unroll
            for (int r = 0; r < 8; ++r) {
                float4 x = *(const float4*)&Xl[(rg * 8 + r) * 128 + kt * 32 + k4 * 4];
                acc[r].x += x.x * w0.x + x.y * w1.x + x.z * w2.x + x.w * w3.x;
                acc[r].y += x.x * w0.y + x.y * w1.y + x.z * w2.y + x.w * w3.y;
                acc[r].z += x.x * w0.z + x.y * w1.z + x.z * w2.z + x.w * w3.z;
                acc[r].w += x.x * w0.w + x.y * w1.w + x.z * w2.w + x.w * w3.w;
            }
        }
        __syncthreads();
    }
    float* Xps = a.Xps[g];
    const float* dinv = a.dinv[g];
#pragma unroll
    for (int r = 0; r < 8; ++r) {
        int row = row0 + rg * 8 + r;
        if (row < n) {
            float dd = dinv[row];
            float4 v = acc[r];
            ((float4*)Xps)[(size_t)row * 32 + (c4 >> 2)] =
                make_float4(v.x * dd, v.y * dd, v.z * dd, v.w * dd);
        }
    }
}

// ---- aggregation: out[d] = dinv[d] * (Xps[d] + sum_{e in in(d)} Xps[src_e]) --
// one 64-lane wave per node; lane owns float2 (2 features)
__global__ __launch_bounds__(256) void agg_kernel(GArgs a, int g0, int n) {
    int g = g0 + blockIdx.y;
    int wave = (blockIdx.x * 256 + threadIdx.x) >> 6;
    if (wave >= n) return;
    int lane = threadIdx.x & 63;
    const float2* Xp2 = (const float2*)a.Xps[g];
    const int* sorted = a.sorted[g];
    int beg = a.offsets[g][wave];
    int cnt = a.counts[g][wave];
    float2 acc = Xp2[(size_t)wave * 64 + lane];
    for (int j = 0; j < cnt;) {
        int m = min(cnt - j, 64);
        int s = (j + lane < cnt) ? sorted[beg + j + lane] : 0;
        for (int k = 0; k < m; ++k) {
            int sk = __shfl(s, k, 64);
            float2 v = Xp2[(size_t)sk * 64 + lane];
            acc.x += v.x;
            acc.y += v.y;
        }
        j += m;
    }
    float dd = a.dinv[g][wave];
    ((float2*)a.out[g])[(size_t)wave * 64 + lane] = make_float2(acc.x * dd, acc.y * dd);
}

extern "C" void kernel_launch(void* const* d_in, const int* in_sizes, int n_in,
                              void* d_out, int out_size, void* d_ws, size_t ws_size,
                              hipStream_t stream) {
    const float* Xin[NG] = {(const float*)d_in[0], (const float*)d_in[1], (const float*)d_in[2]};
    const int* ei[NG] = {(const int*)d_in[3], (const int*)d_in[4], (const int*)d_in[5]};
    const float* Wk[NG] = {(const float*)d_in[6], (const float*)d_in[8], (const float*)d_in[10]};
    const float* bk[NG] = {(const float*)d_in[7], (const float*)d_in[9], (const float*)d_in[11]};

    const int N = in_sizes[0] / F_DIM;  // 50000
    const int E = in_sizes[3] / 2;      // 800000
    float* out = (float*)d_out;

    const size_t xps_b = (size_t)N * F_DIM * 4;
    const size_t sorted_b = (size_t)E * 4;
    const size_t nb = (size_t)N * 4;
    const size_t per = ((xps_b + sorted_b + 4 * nb + 16 + 255) / 256) * 256;
    const bool fused = ws_size >= (size_t)NG * per;
    char* base = (char*)d_ws;

    GArgs a;
    for (int r = 0; r < NG; ++r) {
        char* s = base + (size_t)(fused ? r : 0) * per;
        a.Xps[r] = (float*)s;
        a.sorted[r] = (int*)(s + xps_b);
        a.counts[r] = (int*)(s + xps_b + sorted_b);
        a.offsets[r] = (int*)(s + xps_b + sorted_b + nb);
        a.cursor[r] = (int*)(s + xps_b + sorted_b + 2 * nb);
        a.dinv[r] = (float*)(s + xps_b + sorted_b + 3 * nb);
        a.src[r] = ei[r];
        a.dst[r] = ei[r] + E;
        a.X[r] = Xin[r];
        a.W[r] = Wk[r];
        a.b[r] = bk[r];
        a.out[r] = out + (size_t)r * N * F_DIM;
    }
    a.totals = (int*)(base + xps_b + sorted_b + 4 * nb);  // tail of slot 0

    const dim3 blk(256);
    const int gE = (E + 255) / 256;
    const int gN = (N + 255) / 256;
    const int gR = (N + 63) / 64;
    const int gA = (N * 64 + 255) / 256;

    if (fused) {
        for (int r = 0; r < NG; ++r) hipMemsetAsync(a.counts[r], 0, nb, stream);
        hipMemsetAsync(a.totals, 0, NG * sizeof(int), stream);
        hist_kernel<<<dim3(gE, NG), blk, 0, stream>>>(a, 0, E);
        offs_kernel<<<dim3(gN, NG), blk, 0, stream>>>(a, 0, N);
        build_kernel<<<dim3(gE, NG), blk, 0, stream>>>(a, 0, E);
        gemm_kernel<<<dim3(gR, NG), blk, 0, stream>>>(a, 0, N);
        agg_kernel<<<dim3(gA, NG), blk, 0, stream>>>(a, 0, N);
    } else {
        for (int g = 0; g < NG; ++g) {
            hipMemsetAsync(a.counts[g], 0, nb, stream);
            hipMemsetAsync(a.totals, 0, NG * sizeof(int), stream);
            hist_kernel<<<dim3(gE, 1), blk, 0, stream>>>(a, g, E);
            offs_kernel<<<dim3(gN, 1), blk, 0, stream>>>(a, g, N);
            build_kernel<<<dim3(gE, 1), blk, 0, stream>>>(a, g, E);
            gemm_kernel<<<dim3(gR, 1), blk, 0, stream>>>(a, g, N);
            agg_kernel<<<dim3(gA, 1), blk, 0, stream>>>(a, g, N);
        }
    }
}

// Round 4
// 541.834 us; speedup vs baseline: 8.1791x; 1.2301x over previous
//
#include <hip/hip_runtime.h>

#define F_DIM 128
#define NG 3

typedef __attribute__((ext_vector_type(8))) short short8_t;
typedef __attribute__((ext_vector_type(4))) float f32x4;

__device__ __forceinline__ unsigned short f2bf(float f) {
    unsigned int x = __float_as_uint(f);
    unsigned int r = x + 0x7fffu + ((x >> 16) & 1u);  // RNE
    return (unsigned short)(r >> 16);
}
__device__ __forceinline__ float bflo(unsigned int u) { return __uint_as_float(u << 16); }
__device__ __forceinline__ float bfhi(unsigned int u) { return __uint_as_float(u & 0xffff0000u); }

struct GArgs {
    const int* src[NG]; const int* dst[NG];
    const float* X[NG]; const float* W[NG]; const float* b[NG];
    float* out[NG];
    unsigned short* Xps[NG];  // bf16 [N][128]
    int* counts[NG]; int* offsets[NG]; int* cursor[NG];
    float* dinv[NG]; int* sorted[NG];
    int* totals;  // [NG]
};

// ---- histogram ---------------------------------------------------------------
__global__ __launch_bounds__(256) void hist_kernel(GArgs a, int g0, int E) {
    int g = g0 + blockIdx.y;
    int e = blockIdx.x * 256 + threadIdx.x;
    if (e < E) atomicAdd(&a.counts[g][a.dst[g][e]], 1);
}

// ---- offsets via wave-scan + one atomic per wave (order-free buckets) --------
__global__ __launch_bounds__(256) void offs_kernel(GArgs a, int g0, int n) {
    int g = g0 + blockIdx.y;
    int i = blockIdx.x * 256 + threadIdx.x;
    int lane = threadIdx.x & 63;
    int c = (i < n) ? a.counts[g][i] : 0;
    int v = c;
#pragma unroll
    for (int off = 1; off < 64; off <<= 1) {
        int u = __shfl_up(v, off, 64);
        if (lane >= off) v += u;
    }
    int wsum = __shfl(v, 63, 64);
    int base = 0;
    if (lane == 63) base = atomicAdd(&a.totals[g], wsum);
    base = __shfl(base, 63, 64);
    int off0 = base + v - c;
    if (i < n) {
        a.offsets[g][i] = off0;
        a.cursor[g][i] = off0;
        a.dinv[g][i] = rsqrtf((float)c + 1.0f);
    }
}

// ---- bucket-scatter ----------------------------------------------------------
__global__ __launch_bounds__(256) void build_kernel(GArgs a, int g0, int E) {
    int g = g0 + blockIdx.y;
    int e = blockIdx.x * 256 + threadIdx.x;
    if (e >= E) return;
    int d = a.dst[g][e];
    int p = atomicAdd(&a.cursor[g][d], 1);
    a.sorted[g][p] = a.src[g][e];
}

// ---- MFMA bf16 GEMM: Xps(bf16) = dinv[row] * (X @ W + b) ---------------------
// 256 thr = 4 waves (2x2), block tile 128x128, wave tile 64x64 (4x4 of 16x16).
// m97 structure: per K-step 8 ds_read_b128 + 16 mfma_f32_16x16x32_bf16.
// LDS: Xl[128][128] bf16 + Wt[128][128] bf16 (=W^T), both XOR-swizzled
// (byte ^= (row&15)<<4) so 16-lane column reads are <=2-way bank aliased.
__global__ __launch_bounds__(256) void gemm_kernel(GArgs a, int g0, int n) {
    int g = g0 + blockIdx.y;
    __shared__ unsigned short Xl[128 * 128];
    __shared__ unsigned short Wt[128 * 128];
    const int t = threadIdx.x;
    const int row0 = blockIdx.x * 128;
    const float* X = a.X[g];
    const float* W = a.W[g];
    char* XlB = (char*)Xl;
    char* WtB = (char*)Wt;

    // stage X tile: chunk i = (row r, 8-float group kc)
    for (int i = t; i < 128 * 16; i += 256) {
        int r = i >> 4, kc = i & 15;
        int row = row0 + r;
        float4 x0 = make_float4(0.f, 0.f, 0.f, 0.f), x1 = x0;
        if (row < n) {
            const float4* xp = (const float4*)(X + (size_t)row * F_DIM + kc * 8);
            x0 = xp[0]; x1 = xp[1];
        }
        uint4 pk;
        pk.x = (unsigned)f2bf(x0.x) | ((unsigned)f2bf(x0.y) << 16);
        pk.y = (unsigned)f2bf(x0.z) | ((unsigned)f2bf(x0.w) << 16);
        pk.z = (unsigned)f2bf(x1.x) | ((unsigned)f2bf(x1.y) << 16);
        pk.w = (unsigned)f2bf(x1.z) | ((unsigned)f2bf(x1.w) << 16);
        unsigned int ad = (unsigned)((r << 8) + (kc << 4)) ^ (unsigned)((r & 15) << 4);
        *(uint4*)(XlB + ad) = pk;
    }
    // stage W^T: task i = (col nn, 8-k group kc); reads coalesced over nn
    for (int i = t; i < 128 * 16; i += 256) {
        int nn = i & 127, kc = i >> 7;
        const float* wp = W + (size_t)(kc * 8) * F_DIM + nn;
        uint4 pk;
        pk.x = (unsigned)f2bf(wp[0])   | ((unsigned)f2bf(wp[128]) << 16);
        pk.y = (unsigned)f2bf(wp[256]) | ((unsigned)f2bf(wp[384]) << 16);
        pk.z = (unsigned)f2bf(wp[512]) | ((unsigned)f2bf(wp[640]) << 16);
        pk.w = (unsigned)f2bf(wp[768]) | ((unsigned)f2bf(wp[896]) << 16);
        unsigned int ad = (unsigned)((nn << 8) + (kc << 4)) ^ (unsigned)((nn & 15) << 4);
        *(uint4*)(WtB + ad) = pk;
    }
    __syncthreads();

    const int l = t & 63;
    const int wv = t >> 6;
    const int wr = wv >> 1, wc = wv & 1;
    const int lm = l & 15;  // m (A) / n (B) within 16-tile
    const int lk = l >> 4;  // k-group 0..3 (8 contiguous k each)

    f32x4 acc[4][4] = {};
#pragma unroll
    for (int ks = 0; ks < 4; ++ks) {
        const int kb = ks * 64 + lk * 16;  // byte offset of this lane's 8 bf16
        short8_t af[4], bv[4];
#pragma unroll
        for (int mt = 0; mt < 4; ++mt) {
            int r = wr * 64 + mt * 16 + lm;
            unsigned int ad = (unsigned)((r << 8) + kb) ^ (unsigned)((r & 15) << 4);
            af[mt] = *(const short8_t*)(XlB + ad);
        }
#pragma unroll
        for (int nt = 0; nt < 4; ++nt) {
            int c = wc * 64 + nt * 16 + lm;
            unsigned int ad = (unsigned)((c << 8) + kb) ^ (unsigned)((c & 15) << 4);
            bv[nt] = *(const short8_t*)(WtB + ad);
        }
#pragma unroll
        for (int mt = 0; mt < 4; ++mt)
#pragma unroll
            for (int nt = 0; nt < 4; ++nt)
                acc[mt][nt] = __builtin_amdgcn_mfma_f32_16x16x32_bf16(af[mt], bv[nt],
                                                                      acc[mt][nt], 0, 0, 0);
    }

    // epilogue: C/D layout col=lane&15, row=(lane>>4)*4+reg
    const float* bia = a.b[g];
    const float* dinv = a.dinv[g];
    unsigned short* Xps = a.Xps[g];
#pragma unroll
    for (int nt = 0; nt < 4; ++nt) {
        int col = wc * 64 + nt * 16 + lm;
        float bc = bia[col];
#pragma unroll
        for (int mt = 0; mt < 4; ++mt) {
            int rbase = row0 + wr * 64 + mt * 16 + lk * 4;
#pragma unroll
            for (int r = 0; r < 4; ++r) {
                int row = rbase + r;
                if (row < n) {
                    float v = (acc[mt][nt][r] + bc) * dinv[row];
                    Xps[(size_t)row * F_DIM + col] = f2bf(v);
                }
            }
        }
    }
}

// ---- aggregation: out[d] = dinv[d] * (Xps[d] + sum Xps[src_e]), bf16 gathers -
__global__ __launch_bounds__(256) void agg_kernel(GArgs a, int g0, int n) {
    int g = g0 + blockIdx.y;
    int wave = (blockIdx.x * 256 + threadIdx.x) >> 6;
    if (wave >= n) return;
    int lane = threadIdx.x & 63;
    const unsigned int* Xp = (const unsigned int*)a.Xps[g];  // 64 u32 per row
    const int* sorted = a.sorted[g];
    int beg = a.offsets[g][wave];
    int cnt = a.counts[g][wave];
    unsigned int u0 = Xp[(size_t)wave * 64 + lane];
    float ax = bflo(u0), ay = bfhi(u0);
    for (int j = 0; j < cnt;) {
        int m = min(cnt - j, 64);
        int s = (j + lane < cnt) ? sorted[beg + j + lane] : 0;
        for (int k = 0; k < m; ++k) {
            int sk = __shfl(s, k, 64);
            unsigned int v = Xp[(size_t)sk * 64 + lane];
            ax += bflo(v);
            ay += bfhi(v);
        }
        j += m;
    }
    float dd = a.dinv[g][wave];
    ((float2*)a.out[g])[(size_t)wave * 64 + lane] = make_float2(ax * dd, ay * dd);
}

extern "C" void kernel_launch(void* const* d_in, const int* in_sizes, int n_in,
                              void* d_out, int out_size, void* d_ws, size_t ws_size,
                              hipStream_t stream) {
    const float* Xin[NG] = {(const float*)d_in[0], (const float*)d_in[1], (const float*)d_in[2]};
    const int* ei[NG] = {(const int*)d_in[3], (const int*)d_in[4], (const int*)d_in[5]};
    const float* Wk[NG] = {(const float*)d_in[6], (const float*)d_in[8], (const float*)d_in[10]};
    const float* bk[NG] = {(const float*)d_in[7], (const float*)d_in[9], (const float*)d_in[11]};

    const int N = in_sizes[0] / F_DIM;  // 50000
    const int E = in_sizes[3] / 2;      // 800000
    float* out = (float*)d_out;

    const size_t xps_b = (size_t)N * F_DIM * 2;  // bf16
    const size_t sorted_b = (size_t)E * 4;
    const size_t nb = (size_t)N * 4;
    const size_t per = ((xps_b + sorted_b + 4 * nb + 64 + 255) / 256) * 256;
    const bool fused = ws_size >= (size_t)NG * per;
    char* base = (char*)d_ws;

    GArgs a;
    for (int r = 0; r < NG; ++r) {
        char* s = base + (size_t)(fused ? r : 0) * per;
        a.Xps[r] = (unsigned short*)s;
        a.sorted[r] = (int*)(s + xps_b);
        a.counts[r] = (int*)(s + xps_b + sorted_b);
        a.offsets[r] = (int*)(s + xps_b + sorted_b + nb);
        a.cursor[r] = (int*)(s + xps_b + sorted_b + 2 * nb);
        a.dinv[r] = (float*)(s + xps_b + sorted_b + 3 * nb);
        a.src[r] = ei[r];
        a.dst[r] = ei[r] + E;
        a.X[r] = Xin[r];
        a.W[r] = Wk[r];
        a.b[r] = bk[r];
        a.out[r] = out + (size_t)r * N * F_DIM;
    }
    a.totals = (int*)(base + xps_b + sorted_b + 4 * nb);

    const dim3 blk(256);
    const int gE = (E + 255) / 256;
    const int gN = (N + 255) / 256;
    const int gR = (N + 127) / 128;
    const int gA = (N * 64 + 255) / 256;

    if (fused) {
        for (int r = 0; r < NG; ++r) hipMemsetAsync(a.counts[r], 0, nb, stream);
        hipMemsetAsync(a.totals, 0, NG * sizeof(int), stream);
        hist_kernel<<<dim3(gE, NG), blk, 0, stream>>>(a, 0, E);
        offs_kernel<<<dim3(gN, NG), blk, 0, stream>>>(a, 0, N);
        build_kernel<<<dim3(gE, NG), blk, 0, stream>>>(a, 0, E);
        gemm_kernel<<<dim3(gR, NG), blk, 0, stream>>>(a, 0, N);
        agg_kernel<<<dim3(gA, NG), blk, 0, stream>>>(a, 0, N);
    } else {
        for (int g = 0; g < NG; ++g) {
            hipMemsetAsync(a.counts[g], 0, nb, stream);
            hipMemsetAsync(a.totals, 0, NG * sizeof(int), stream);
            hist_kernel<<<dim3(gE, 1), blk, 0, stream>>>(a, g, E);
            offs_kernel<<<dim3(gN, 1), blk, 0, stream>>>(a, g, N);
            build_kernel<<<dim3(gE, 1), blk, 0, stream>>>(a, g, E);
            gemm_kernel<<<dim3(gR, 1), blk, 0, stream>>>(a, g, N);
            agg_kernel<<<dim3(gA, 1), blk, 0, stream>>>(a, g, N);
        }
    }
}

// Round 5
// 465.941 us; speedup vs baseline: 9.5113x; 1.1629x over previous
//
#include <hip/hip_runtime.h>

#define F_DIM 128
#define NG 3
#define XCDS 8
#define EPT 8  // edges per thread in partitioned kernels

typedef __attribute__((ext_vector_type(8))) short short8_t;
typedef __attribute__((ext_vector_type(4))) float f32x4;

__device__ __forceinline__ unsigned short f2bf(float f) {
    unsigned int x = __float_as_uint(f);
    unsigned int r = x + 0x7fffu + ((x >> 16) & 1u);  // RNE
    return (unsigned short)(r >> 16);
}
__device__ __forceinline__ float bflo(unsigned int u) { return __uint_as_float(u << 16); }
__device__ __forceinline__ float bfhi(unsigned int u) { return __uint_as_float(u & 0xffff0000u); }

struct GArgs {
    const int* src[NG]; const int* dst[NG];
    const float* X[NG]; const float* W[NG]; const float* b[NG];
    float* out[NG];
    unsigned short* Xps[NG];  // bf16 [N][128]
    int* counts[NG]; int* offsets[NG]; int* cursor[NG];
    float* dinv[NG]; int* sorted[NG];
    int* totals;  // [NG]
};

// ---- histogram, XCD-partitioned by dst-range ---------------------------------
// block b: xcd = b%8 owns dst in [xcd*nPerX, (xcd+1)*nPerX); chunk = b/8.
// Atomics on counts stay in ONE XCD's L2 (no cross-XCD line ping-pong).
__global__ __launch_bounds__(256) void hist_kernel(GArgs a, int g0, int E, int nPerX) {
    int g = g0 + blockIdx.y;
    int xcd = blockIdx.x % XCDS;
    int lo = xcd * nPerX, hi = lo + nPerX;
    const int* dst = a.dst[g];
    int* counts = a.counts[g];
    int base = (blockIdx.x / XCDS) * (256 * EPT) + threadIdx.x;
#pragma unroll
    for (int i = 0; i < EPT; ++i) {
        int e = base + i * 256;
        if (e < E) {
            int d = dst[e];
            if (d >= lo && d < hi) atomicAdd(&counts[d], 1);
        }
    }
}

// ---- offsets via wave-scan + one atomic per wave (order-free buckets) --------
__global__ __launch_bounds__(256) void offs_kernel(GArgs a, int g0, int n) {
    int g = g0 + blockIdx.y;
    int i = blockIdx.x * 256 + threadIdx.x;
    int lane = threadIdx.x & 63;
    int c = (i < n) ? a.counts[g][i] : 0;
    int v = c;
#pragma unroll
    for (int off = 1; off < 64; off <<= 1) {
        int u = __shfl_up(v, off, 64);
        if (lane >= off) v += u;
    }
    int wsum = __shfl(v, 63, 64);
    int base = 0;
    if (lane == 63) base = atomicAdd(&a.totals[g], wsum);
    base = __shfl(base, 63, 64);
    int off0 = base + v - c;
    if (i < n) {
        a.offsets[g][i] = off0;
        a.cursor[g][i] = off0;
        a.dinv[g][i] = rsqrtf((float)c + 1.0f);
    }
}

// ---- bucket-scatter, XCD-partitioned by dst-range ----------------------------
// Cursor atomics AND sorted-payload writes for a line come from one XCD only.
__global__ __launch_bounds__(256) void build_kernel(GArgs a, int g0, int E, int nPerX) {
    int g = g0 + blockIdx.y;
    int xcd = blockIdx.x % XCDS;
    int lo = xcd * nPerX, hi = lo + nPerX;
    const int* dst = a.dst[g];
    const int* src = a.src[g];
    int* cursor = a.cursor[g];
    int* sorted = a.sorted[g];
    int base = (blockIdx.x / XCDS) * (256 * EPT) + threadIdx.x;
#pragma unroll
    for (int i = 0; i < EPT; ++i) {
        int e = base + i * 256;
        if (e < E) {
            int d = dst[e];
            if (d >= lo && d < hi) {
                int p = atomicAdd(&cursor[d], 1);
                sorted[p] = src[e];
            }
        }
    }
}

// ---- MFMA bf16 GEMM: Xps(bf16) = dinv[row] * (X @ W + b) ---------------------
__global__ __launch_bounds__(256) void gemm_kernel(GArgs a, int g0, int n) {
    int g = g0 + blockIdx.y;
    __shared__ unsigned short Xl[128 * 128];
    __shared__ unsigned short Wt[128 * 128];
    const int t = threadIdx.x;
    const int row0 = blockIdx.x * 128;
    const float* X = a.X[g];
    const float* W = a.W[g];
    char* XlB = (char*)Xl;
    char* WtB = (char*)Wt;

    for (int i = t; i < 128 * 16; i += 256) {
        int r = i >> 4, kc = i & 15;
        int row = row0 + r;
        float4 x0 = make_float4(0.f, 0.f, 0.f, 0.f), x1 = x0;
        if (row < n) {
            const float4* xp = (const float4*)(X + (size_t)row * F_DIM + kc * 8);
            x0 = xp[0]; x1 = xp[1];
        }
        uint4 pk;
        pk.x = (unsigned)f2bf(x0.x) | ((unsigned)f2bf(x0.y) << 16);
        pk.y = (unsigned)f2bf(x0.z) | ((unsigned)f2bf(x0.w) << 16);
        pk.z = (unsigned)f2bf(x1.x) | ((unsigned)f2bf(x1.y) << 16);
        pk.w = (unsigned)f2bf(x1.z) | ((unsigned)f2bf(x1.w) << 16);
        unsigned int ad = (unsigned)((r << 8) + (kc << 4)) ^ (unsigned)((r & 15) << 4);
        *(uint4*)(XlB + ad) = pk;
    }
    for (int i = t; i < 128 * 16; i += 256) {
        int nn = i & 127, kc = i >> 7;
        const float* wp = W + (size_t)(kc * 8) * F_DIM + nn;
        uint4 pk;
        pk.x = (unsigned)f2bf(wp[0])   | ((unsigned)f2bf(wp[128]) << 16);
        pk.y = (unsigned)f2bf(wp[256]) | ((unsigned)f2bf(wp[384]) << 16);
        pk.z = (unsigned)f2bf(wp[512]) | ((unsigned)f2bf(wp[640]) << 16);
        pk.w = (unsigned)f2bf(wp[768]) | ((unsigned)f2bf(wp[896]) << 16);
        unsigned int ad = (unsigned)((nn << 8) + (kc << 4)) ^ (unsigned)((nn & 15) << 4);
        *(uint4*)(WtB + ad) = pk;
    }
    __syncthreads();

    const int l = t & 63;
    const int wv = t >> 6;
    const int wr = wv >> 1, wc = wv & 1;
    const int lm = l & 15;
    const int lk = l >> 4;

    f32x4 acc[4][4] = {};
#pragma unroll
    for (int ks = 0; ks < 4; ++ks) {
        const int kb = ks * 64 + lk * 16;
        short8_t af[4], bv[4];
#pragma unroll
        for (int mt = 0; mt < 4; ++mt) {
            int r = wr * 64 + mt * 16 + lm;
            unsigned int ad = (unsigned)((r << 8) + kb) ^ (unsigned)((r & 15) << 4);
            af[mt] = *(const short8_t*)(XlB + ad);
        }
#pragma unroll
        for (int nt = 0; nt < 4; ++nt) {
            int c = wc * 64 + nt * 16 + lm;
            unsigned int ad = (unsigned)((c << 8) + kb) ^ (unsigned)((c & 15) << 4);
            bv[nt] = *(const short8_t*)(WtB + ad);
        }
#pragma unroll
        for (int mt = 0; mt < 4; ++mt)
#pragma unroll
            for (int nt = 0; nt < 4; ++nt)
                acc[mt][nt] = __builtin_amdgcn_mfma_f32_16x16x32_bf16(af[mt], bv[nt],
                                                                      acc[mt][nt], 0, 0, 0);
    }

    const float* bia = a.b[g];
    const float* dinv = a.dinv[g];
    unsigned short* Xps = a.Xps[g];
#pragma unroll
    for (int nt = 0; nt < 4; ++nt) {
        int col = wc * 64 + nt * 16 + lm;
        float bc = bia[col];
#pragma unroll
        for (int mt = 0; mt < 4; ++mt) {
            int rbase = row0 + wr * 64 + mt * 16 + lk * 4;
#pragma unroll
            for (int r = 0; r < 4; ++r) {
                int row = rbase + r;
                if (row < n) {
                    float v = (acc[mt][nt][r] + bc) * dinv[row];
                    Xps[(size_t)row * F_DIM + col] = f2bf(v);
                }
            }
        }
    }
}

// ---- aggregation: out[d] = dinv[d] * (Xps[d] + sum Xps[src_e]), bf16 gathers -
__global__ __launch_bounds__(256) void agg_kernel(GArgs a, int g0, int n) {
    int g = g0 + blockIdx.y;
    int wave = (blockIdx.x * 256 + threadIdx.x) >> 6;
    if (wave >= n) return;
    int lane = threadIdx.x & 63;
    const unsigned int* Xp = (const unsigned int*)a.Xps[g];
    const int* sorted = a.sorted[g];
    int beg = a.offsets[g][wave];
    int cnt = a.counts[g][wave];
    unsigned int u0 = Xp[(size_t)wave * 64 + lane];
    float ax = bflo(u0), ay = bfhi(u0);
    for (int j = 0; j < cnt;) {
        int m = min(cnt - j, 64);
        int s = (j + lane < cnt) ? sorted[beg + j + lane] : 0;
        for (int k = 0; k < m; ++k) {
            int sk = __shfl(s, k, 64);
            unsigned int v = Xp[(size_t)sk * 64 + lane];
            ax += bflo(v);
            ay += bfhi(v);
        }
        j += m;
    }
    float dd = a.dinv[g][wave];
    ((float2*)a.out[g])[(size_t)wave * 64 + lane] = make_float2(ax * dd, ay * dd);
}

extern "C" void kernel_launch(void* const* d_in, const int* in_sizes, int n_in,
                              void* d_out, int out_size, void* d_ws, size_t ws_size,
                              hipStream_t stream) {
    const float* Xin[NG] = {(const float*)d_in[0], (const float*)d_in[1], (const float*)d_in[2]};
    const int* ei[NG] = {(const int*)d_in[3], (const int*)d_in[4], (const int*)d_in[5]};
    const float* Wk[NG] = {(const float*)d_in[6], (const float*)d_in[8], (const float*)d_in[10]};
    const float* bk[NG] = {(const float*)d_in[7], (const float*)d_in[9], (const float*)d_in[11]};

    const int N = in_sizes[0] / F_DIM;  // 50000
    const int E = in_sizes[3] / 2;      // 800000
    float* out = (float*)d_out;

    const size_t xps_b = (size_t)N * F_DIM * 2;  // bf16
    const size_t sorted_b = (size_t)E * 4;
    const size_t nb = (size_t)N * 4;
    const size_t per = ((xps_b + sorted_b + 5 * nb + 64 + 255) / 256) * 256;
    const bool fused = ws_size >= (size_t)NG * per;
    char* base = (char*)d_ws;

    GArgs a;
    for (int r = 0; r < NG; ++r) {
        char* s = base + (size_t)(fused ? r : 0) * per;
        a.Xps[r] = (unsigned short*)s;
        a.sorted[r] = (int*)(s + xps_b);
        a.counts[r] = (int*)(s + xps_b + sorted_b);
        a.offsets[r] = (int*)(s + xps_b + sorted_b + nb);
        a.cursor[r] = (int*)(s + xps_b + sorted_b + 2 * nb);
        a.dinv[r] = (float*)(s + xps_b + sorted_b + 3 * nb);
        a.src[r] = ei[r];
        a.dst[r] = ei[r] + E;
        a.X[r] = Xin[r];
        a.W[r] = Wk[r];
        a.b[r] = bk[r];
        a.out[r] = out + (size_t)r * N * F_DIM;
    }
    a.totals = (int*)(base + xps_b + sorted_b + 4 * nb);  // inside slot-0 padding

    const dim3 blk(256);
    const int nPerX = (N + XCDS - 1) / XCDS;
    const int chunks = (E + 256 * EPT - 1) / (256 * EPT);
    const int gP = chunks * XCDS;  // partitioned kernels
    const int gN = (N + 255) / 256;
    const int gR = (N + 127) / 128;
    const int gA = (N * 64 + 255) / 256;

    if (fused) {
        for (int r = 0; r < NG; ++r) hipMemsetAsync(a.counts[r], 0, nb, stream);
        hipMemsetAsync(a.totals, 0, NG * sizeof(int), stream);
        hist_kernel<<<dim3(gP, NG), blk, 0, stream>>>(a, 0, E, nPerX);
        offs_kernel<<<dim3(gN, NG), blk, 0, stream>>>(a, 0, N);
        build_kernel<<<dim3(gP, NG), blk, 0, stream>>>(a, 0, E, nPerX);
        gemm_kernel<<<dim3(gR, NG), blk, 0, stream>>>(a, 0, N);
        agg_kernel<<<dim3(gA, NG), blk, 0, stream>>>(a, 0, N);
    } else {
        for (int g = 0; g < NG; ++g) {
            hipMemsetAsync(a.counts[g], 0, nb, stream);
            hipMemsetAsync(a.totals, 0, NG * sizeof(int), stream);
            hist_kernel<<<dim3(gP, 1), blk, 0, stream>>>(a, g, E, nPerX);
            offs_kernel<<<dim3(gN, 1), blk, 0, stream>>>(a, g, N);
            build_kernel<<<dim3(gP, 1), blk, 0, stream>>>(a, g, E, nPerX);
            gemm_kernel<<<dim3(gR, 1), blk, 0, stream>>>(a, g, N);
            agg_kernel<<<dim3(gA, 1), blk, 0, stream>>>(a, g, N);
        }
    }
}